// Round 3
// baseline (306.406 us; speedup 1.0000x reference)
//
#include <hip/hip_runtime.h>
#include <hip/hip_bf16.h>

typedef __bf16 bf16_t;
typedef bf16_t bf16x8 __attribute__((ext_vector_type(8)));
typedef bf16_t bf16x4 __attribute__((ext_vector_type(4)));
typedef float f32x4 __attribute__((ext_vector_type(4)));

// H=8 D=31 T=4 P=50 C=248 O=744 B=512, DT=124, SCALE=31^-0.5
constexpr float SCALE = 0.17960530202677491f;

// LDS byte offsets (total 157,984 <= 163,840)
#define XT_OFF   0           // xT[200][256] bf16, 32x16B chunks, hash (n>>1)&7 (102,400 B)
#define QH_OFF   102400      // qh[50][128] bf16, swizzled           (12,800 B)
#define KH_OFF   115200      // kh[50][128] bf16, swizzled           (12,800 B)
#define AS_OFF   115200      // As[64][64] bf16 (aliases kh)         (8,192 B)
#define VT_OFF   128000      // vT[128][64] bf16, swizzled           (16,384 B)
#define LS_OFF   144384      // Ls[50][68] f32                       (13,600 B)
#define SMEM_BYTES 157984

__device__ __forceinline__ f32x4 mfma16(bf16x8 a, bf16x8 b, f32x4 c) {
    return __builtin_amdgcn_mfma_f32_16x16x32_bf16(a, b, c, 0, 0, 0);
}

// ---------------------------------------------------------------------------
// prep: pack W into per-(head,mtile,kstep) fragment-contiguous blocks,
// rel into fragment-contiguous blocks (7 rt-tiles, rows 99..111 zero),
// bias into bp[h][96].
// ---------------------------------------------------------------------------
__global__ void prep_kernel(const float* __restrict__ w, const float* __restrict__ b_qkv,
                            const float* __restrict__ rel,
                            bf16_t* __restrict__ Wf, bf16_t* __restrict__ relf,
                            float* __restrict__ bp)
{
    int i = blockIdx.x * 256 + threadIdx.x;
    if (i < 196608) {                    // Wf
        int e = i & 7, lane = (i >> 3) & 63;
        int f = i >> 9;                  // (h*6+m)*8+ks
        int ks = f & 7, g = f >> 3;
        int h = g / 6, m = g - h * 6;
        int r15 = lane & 15, g4 = lane >> 4;
        int s = m >> 1, d = ((m & 1) << 4) + r15;
        int c = ks * 32 + g4 * 8 + e;
        float v = 0.f;
        if (d < 31 && c < 248) v = w[(long)(s * 248 + h * 31 + d) * 248 + c];
        Wf[i] = (bf16_t)v;
        return;
    }
    i -= 196608;
    if (i < 14336) {                     // relf: rt 0..6
        int e = i & 7, lane = (i >> 3) & 63;
        int f = i >> 9;                  // rt*4+ks
        int ks = f & 3, rt = f >> 2;
        int r = rt * 16 + (lane & 15);
        int dt = ks * 32 + (lane >> 4) * 8 + e;
        float v = 0.f;
        if (r < 99 && dt < 124) v = rel[r * 124 + dt];
        relf[i] = (bf16_t)v;
        return;
    }
    i -= 14336;
    if (i < 768) {                       // bp[h][96]
        int h = i / 96, row = i - h * 96;
        int s = row >> 5, d = row & 31;
        bp[i] = (d < 31) ? b_qkv[s * 248 + h * 31 + d] : 0.f;
    }
}

// ---------------------------------------------------------------------------
// Fused kernel: one block per batch b. 1024 threads = 16 waves.
// ---------------------------------------------------------------------------
__global__ __launch_bounds__(1024, 4)
void fused_kernel(const float* __restrict__ x, const bf16_t* __restrict__ Wf,
                  const bf16_t* __restrict__ relf, const float* __restrict__ bp,
                  float* __restrict__ out)
{
    extern __shared__ char smem[];
    const int b    = blockIdx.x;
    const int tid  = threadIdx.x;
    const int lane = tid & 63;
    const int w    = tid >> 6;           // 0..15
    const int r15  = lane & 15, g4 = lane >> 4;

    // ================= phase 0: zero pads + column-read transpose staging ====
    // zero vT entirely (pad cols p=50..63 and rows i=124..127 must stay 0)
    *(f32x4*)(smem + VT_OFF + tid * 16) = f32x4{0.f, 0.f, 0.f, 0.f};
    // zero qh/kh dt-pad (cols 124..127); persists across heads
    if (tid < 100) {
        int p = tid >> 1;
        int base = (tid & 1) ? KH_OFF : QH_OFF;
        int chunk = 15 ^ (p & 7);
        *(long*)(smem + base + p * 256 + chunk * 16 + 8) = 0L;
    }
    {
        const int n  = tid & 255;        // column of x[b] (= flat p*4+t)
        const int cg = tid >> 8;         // c-range group, 64 c's each
        if (n < 200) {
            const float* xb = x + (long)b * 49600 + n;
            const int hash = (n >> 1) & 7;
#pragma unroll
            for (int cb = 0; cb < 8; ++cb) {
                bf16x8 pk;
#pragma unroll
                for (int e = 0; e < 8; ++e) {
                    int c = cg * 64 + cb * 8 + e;
                    float v = (c < 248) ? xb[(long)c * 200] : 0.f;
                    pk[e] = (bf16_t)v;
                }
                *(bf16x8*)(smem + XT_OFF + n * 512 + (((cg * 8 + cb) ^ hash) << 4)) = pk;
            }
        }
    }
    __syncthreads();

    // ================= phase 1: A fragments into registers ===================
    // wave w: mu = w>>3 (m-trio), nu = w&7 (n-pair: nt = nu*2+ui)
    const int mu = w >> 3;
    const int nu = w & 7;
    bf16x8 Areg[2][8];
#pragma unroll
    for (int ui = 0; ui < 2; ++ui) {
        int n = (nu * 2 + ui) * 16 + r15;
        int hash = (n >> 1) & 7;
#pragma unroll
        for (int ks = 0; ks < 8; ++ks) {
            bf16x8 v = {};
            if (n < 200)
                v = *(const bf16x8*)(smem + XT_OFF + n * 512 + ((((ks << 2) | g4) ^ hash) << 4));
            Areg[ui][ks] = v;
        }
    }
    // no barrier: xT is never written again; next phase writes qh/kh/vT only

    const int ptile = w >> 2, cq = w & 3;     // scores roles
    const int it = w >> 1, psel = w & 1;      // PV roles

    // ================= head loop =================
    for (int h = 0; h < 8; ++h) {
        // ---- qkv GEMM: A from regs, B from global frag-packed Wf ----
#pragma unroll
        for (int m3 = 0; m3 < 3; ++m3) {
            int m = mu * 3 + m3;
            int s = m >> 1;
            int d = ((m & 1) << 4) + r15;          // 0..31
            float bias = bp[h * 96 + m * 16 + r15];
            f32x4 acc0 = f32x4{0.f, 0.f, 0.f, 0.f};
            f32x4 acc1 = f32x4{0.f, 0.f, 0.f, 0.f};
            const bf16_t* wfrag = Wf + ((long)((h * 6 + m) * 8) << 9) + lane * 8;
#pragma unroll
            for (int ks = 0; ks < 8; ++ks) {
                bf16x8 Bf = *(const bf16x8*)(wfrag + (ks << 9));
                acc0 = mfma16(Areg[0][ks], Bf, acc0);
                acc1 = mfma16(Areg[1][ks], Bf, acc1);
            }
            if (d < 31) {
#pragma unroll
                for (int ui = 0; ui < 2; ++ui) {
                    f32x4 a = ui ? acc1 : acc0;
                    int p = (nu * 2 + ui) * 4 + g4;
                    if (p >= 50) continue;
                    float a0 = a[0] + bias, a1 = a[1] + bias;
                    float a2 = a[2] + bias, a3 = a[3] + bias;
                    if (s < 2) {
                        bf16x4 pk = {(bf16_t)a0, (bf16_t)a1, (bf16_t)a2, (bf16_t)a3};
                        int base = (s == 0) ? QH_OFF : KH_OFF;
                        int chunk = (d >> 1) ^ (p & 7);
                        *(bf16x4*)(smem + base + p * 256 + chunk * 16 + ((d & 1) << 3)) = pk;
                    } else {
                        int chunk = ((p >> 3) ^ (d & 7)) << 4;
                        int vbase = VT_OFF + (d * 4) * 128 + chunk + (p & 7) * 2;
                        *(bf16_t*)(smem + vbase)       = (bf16_t)a0;
                        *(bf16_t*)(smem + vbase + 128) = (bf16_t)a1;
                        *(bf16_t*)(smem + vbase + 256) = (bf16_t)a2;
                        *(bf16_t*)(smem + vbase + 384) = (bf16_t)a3;
                    }
                }
            }
        }
        __syncthreads();

        // ---- scores: wave (ptile, cq): dots tile ct=cq, rel tiles rt=cq, cq+4 ----
        bf16x8 Afr[4];
        {
            int p = ptile * 16 + r15;
            int hp = p & 7;
#pragma unroll
            for (int ks = 0; ks < 4; ++ks)
                Afr[ks] = *(const bf16x8*)(smem + QH_OFF + p * 256 + ((((ks << 2) | g4) ^ hp) << 4));
        }
        f32x4 s0 = f32x4{0.f, 0.f, 0.f, 0.f};
        f32x4 s1 = f32x4{0.f, 0.f, 0.f, 0.f};
        f32x4 s2 = f32x4{0.f, 0.f, 0.f, 0.f};
        {   // dots: kh cols ct=cq
            int c = cq * 16 + r15;
            int hc = c & 7;
#pragma unroll
            for (int ks = 0; ks < 4; ++ks) {
                bf16x8 Bf = *(const bf16x8*)(smem + KH_OFF + c * 256 + ((((ks << 2) | g4) ^ hc) << 4));
                s0 = mfma16(Afr[ks], Bf, s0);
            }
        }
        {   // rel rows rt = cq (r = cq*16 + r15)
            const bf16_t* rf = relf + ((long)(cq * 4) << 9) + lane * 8;
#pragma unroll
            for (int ks = 0; ks < 4; ++ks) {
                bf16x8 Bf = *(const bf16x8*)(rf + (ks << 9));
                s1 = mfma16(Afr[ks], Bf, s1);
            }
        }
        if (cq < 3) {   // rel rows rt = cq+4 (r = (cq+4)*16 + r15), covers r<=111
            const bf16_t* rf = relf + ((long)((cq + 4) * 4) << 9) + lane * 8;
#pragma unroll
            for (int ks = 0; ks < 4; ++ks) {
                bf16x8 Bf = *(const bf16x8*)(rf + (ks << 9));
                s2 = mfma16(Afr[ks], Bf, s2);
            }
        }
        // pass A: store dots into Ls
        {
            int c = cq * 16 + r15;
            if (c < 50) {
#pragma unroll
                for (int j = 0; j < 4; ++j) {
                    int qrow = ptile * 16 + g4 * 4 + j;
                    if (qrow < 50)
                        *(float*)(smem + LS_OFF + (qrow * 68 + c) * 4) = s0[j];
                }
            }
        }
        __syncthreads();
        // pass B: scatter-add rel bias: jj = r + qrow - 49
        {
            int r = cq * 16 + r15;
#pragma unroll
            for (int j = 0; j < 4; ++j) {
                int qrow = ptile * 16 + g4 * 4 + j;
                int jj = r + qrow - 49;
                if (qrow < 50 && jj >= 0 && jj < 50)
                    *(float*)(smem + LS_OFF + (qrow * 68 + jj) * 4) += s1[j];
            }
        }
        if (cq < 3) {
            int r = (cq + 4) * 16 + r15;
#pragma unroll
            for (int j = 0; j < 4; ++j) {
                int qrow = ptile * 16 + g4 * 4 + j;
                int jj = r + qrow - 49;
                if (qrow < 50 && jj >= 0 && jj < 50)
                    *(float*)(smem + LS_OFF + (qrow * 68 + jj) * 4) += s2[j];
            }
        }
        __syncthreads();
        // ---- softmax (16 lanes per row), write As (aliases kh) ----
        {
            int row = tid >> 4, sub = tid & 15;
            if (row < 50) {
                float mx = -1e30f;
                for (int jj = sub; jj < 50; jj += 16)
                    mx = fmaxf(mx, *(const float*)(smem + LS_OFF + (row * 68 + jj) * 4));
                mx = fmaxf(mx, __shfl_xor(mx, 1));
                mx = fmaxf(mx, __shfl_xor(mx, 2));
                mx = fmaxf(mx, __shfl_xor(mx, 4));
                mx = fmaxf(mx, __shfl_xor(mx, 8));
                float sum = 0.f;
                for (int jj = sub; jj < 50; jj += 16) {
                    float* pL = (float*)(smem + LS_OFF + (row * 68 + jj) * 4);
                    float e = __expf((*pL - mx) * SCALE);
                    *pL = e;
                    sum += e;
                }
                sum += __shfl_xor(sum, 1);
                sum += __shfl_xor(sum, 2);
                sum += __shfl_xor(sum, 4);
                sum += __shfl_xor(sum, 8);
                float rs = 1.f / sum;
                int hrow = row & 7;
                for (int jj = sub; jj < 64; jj += 16) {
                    float v = 0.f;
                    if (jj < 50)
                        v = *(const float*)(smem + LS_OFF + (row * 68 + jj) * 4) * rs;
                    *(bf16_t*)(smem + AS_OFF + row * 128 + (((jj >> 3) ^ hrow) << 4) + (jj & 7) * 2) = (bf16_t)v;
                }
            }
        }
        __syncthreads();
        // ---- PV: wave (it, psel): C[i][p], i-tile it, p-tiles 2*psel..2*psel+1 ----
        {
            bf16x8 Av[2];
            int irow = it * 16 + r15;
            int hv = (irow >> 2) & 7;
#pragma unroll
            for (int ks = 0; ks < 2; ++ks)
                Av[ks] = *(const bf16x8*)(smem + VT_OFF + irow * 128 + ((((ks << 2) | g4) ^ hv) << 4));
            int dd = it * 4 + g4;
#pragma unroll
            for (int pi = 0; pi < 2; ++pi) {
                int pt = psel * 2 + pi;
                int prow = pt * 16 + r15;
                int hp2 = prow & 7;
                f32x4 po = f32x4{0.f, 0.f, 0.f, 0.f};
#pragma unroll
                for (int ks = 0; ks < 2; ++ks) {
                    bf16x8 Bs = *(const bf16x8*)(smem + AS_OFF + prow * 128 + ((((ks << 2) | g4) ^ hp2) << 4));
                    po = mfma16(Av[ks], Bs, po);
                }
                if (dd < 31 && prow < 50)
                    *(f32x4*)(out + ((long)b * 248 + h * 31 + dd) * 200 + prow * 4) = po;
            }
        }
        __syncthreads();   // protect qh/kh/As/vT/Ls rewrite by next head
    }
}

// ---------------------------------------------------------------------------
extern "C" void kernel_launch(void* const* d_in, const int* in_sizes, int n_in,
                              void* d_out, int out_size, void* d_ws, size_t ws_size,
                              hipStream_t stream)
{
    const float* x   = (const float*)d_in[0];
    const float* wq  = (const float*)d_in[1];
    const float* bq  = (const float*)d_in[2];
    const float* rel = (const float*)d_in[3];
    float* out = (float*)d_out;

    char* ws = (char*)d_ws;
    bf16_t* Wf   = (bf16_t*)ws;                    // 196,608 elems = 393,216 B
    bf16_t* relf = (bf16_t*)(ws + 393216);         // 14,336 elems  = 28,672 B
    float*  bp   = (float*)(ws + 421888);          // 768 f32       = 3,072 B

    const int B = in_sizes[0] / 49600;

    hipFuncSetAttribute((const void*)fused_kernel,
                        hipFuncAttributeMaxDynamicSharedMemorySize, SMEM_BYTES);

    prep_kernel<<<dim3(828), dim3(256), 0, stream>>>(wq, bq, rel, Wf, relf, bp);
    fused_kernel<<<dim3(B), dim3(1024), SMEM_BYTES, stream>>>(x, Wf, relf, bp, out);
}

// Round 4
// 254.008 us; speedup vs baseline: 1.2063x; 1.2063x over previous
//
#include <hip/hip_runtime.h>
#include <hip/hip_bf16.h>

typedef __bf16 bf16_t;
typedef bf16_t bf16x8 __attribute__((ext_vector_type(8)));
typedef bf16_t bf16x4 __attribute__((ext_vector_type(4)));
typedef float f32x4 __attribute__((ext_vector_type(4)));

// H=8 D=31 T=4 P=50 C=248 O=744 B=512, DT=124, SCALE=31^-0.5
constexpr float SCALE = 0.17960530202677491f;

__device__ __forceinline__ f32x4 mfma16(bf16x8 a, bf16x8 b, f32x4 c) {
    return __builtin_amdgcn_mfma_f32_16x16x32_bf16(a, b, c, 0, 0, 0);
}

__device__ __forceinline__ void wave_lds_fence() {
    // order this wave's LDS ops (cross-lane write->read within one wave)
    asm volatile("s_waitcnt lgkmcnt(0)" ::: "memory");
}

// ---------------------------------------------------------------------------
// prep: W -> per-(head,mtile,kstep) fragment-contiguous, rel -> frag blocks
// (rt 0..6, rows 99..111 zero), bias -> bp[h][96].
// ---------------------------------------------------------------------------
__global__ void prep_kernel(const float* __restrict__ w, const float* __restrict__ b_qkv,
                            const float* __restrict__ rel,
                            bf16_t* __restrict__ Wf, bf16_t* __restrict__ relf,
                            float* __restrict__ bp)
{
    int i = blockIdx.x * 256 + threadIdx.x;
    if (i < 196608) {                    // Wf
        int e = i & 7, lane = (i >> 3) & 63;
        int f = i >> 9;                  // (h*6+m)*8+ks
        int ks = f & 7, g = f >> 3;
        int h = g / 6, m = g - h * 6;
        int r15 = lane & 15, g4 = lane >> 4;
        int s = m >> 1, d = ((m & 1) << 4) + r15;
        int c = ks * 32 + g4 * 8 + e;
        float v = 0.f;
        if (d < 31 && c < 248) v = w[(long)(s * 248 + h * 31 + d) * 248 + c];
        Wf[i] = (bf16_t)v;
        return;
    }
    i -= 196608;
    if (i < 14336) {                     // relf: rt 0..6
        int e = i & 7, lane = (i >> 3) & 63;
        int f = i >> 9;                  // rt*4+ks
        int ks = f & 3, rt = f >> 2;
        int r = rt * 16 + (lane & 15);
        int dt = ks * 32 + (lane >> 4) * 8 + e;
        float v = 0.f;
        if (r < 99 && dt < 124) v = rel[r * 124 + dt];
        relf[i] = (bf16_t)v;
        return;
    }
    i -= 14336;
    if (i < 768) {                       // bp[h][96]
        int h = i / 96, row = i - h * 96;
        int s = row >> 5, d = row & 31;
        bp[i] = (d < 31) ? b_qkv[s * 248 + h * 31 + d] : 0.f;
    }
}

// ---------------------------------------------------------------------------
// Fused kernel: one block per batch b. 256 threads = 4 waves, ~71 KB LDS
// -> 2 blocks/CU co-resident.
// ---------------------------------------------------------------------------
__global__ __launch_bounds__(256, 2)
void fused_kernel(const float* __restrict__ x, const bf16_t* __restrict__ Wf,
                  const bf16_t* __restrict__ relf, const float* __restrict__ bp,
                  float* __restrict__ out)
{
    // swizzled tiles: row-chunk 16B, hash = row&7 (QH/KH/AS), (row>>2)&7 (VT)
    __shared__ __align__(16) bf16_t QH[64][128];   // q[p][dt]
    __shared__ __align__(16) bf16_t KH[64][128];   // k[p'][dt]
    __shared__ __align__(16) bf16_t AS[64][64];    // attn[p][p'] bf16
    __shared__ __align__(16) bf16_t VT[128][64];   // v[i][p']
    __shared__ float LS[50][68];                   // logits[p][p'] f32

    const int b    = blockIdx.x;
    const int tid  = threadIdx.x;
    const int lane = tid & 63;
    const int w    = tid >> 6;           // 0..3
    const int r15  = lane & 15, g4 = lane >> 4;

    // ================= phase 0: zero pads =================
    {
        // VT fully zero (cols p'=50..63, rows i=124..127 must be 0)
        *(f32x4*)((char*)&VT[0][0] + tid * 64)      = f32x4{0.f, 0.f, 0.f, 0.f};
        *(f32x4*)((char*)&VT[0][0] + tid * 64 + 16) = f32x4{0.f, 0.f, 0.f, 0.f};
        *(f32x4*)((char*)&VT[0][0] + tid * 64 + 32) = f32x4{0.f, 0.f, 0.f, 0.f};
        *(f32x4*)((char*)&VT[0][0] + tid * 64 + 48) = f32x4{0.f, 0.f, 0.f, 0.f};
        // QH/KH dt-pad cols 124..127 (chunk 15^hash, upper 8B), rows 0..63
        if (tid < 128) {
            int row = tid & 63;
            char* base = (tid < 64) ? (char*)&QH[0][0] : (char*)&KH[0][0];
            int chunk = 15 ^ (row & 7);
            *(long*)(base + row * 256 + chunk * 16 + 8) = 0L;
        }
    }

    // ================= phase 1: A fragments straight from global x ==========
    // wave w owns columns n = w*64 .. w*64+63 (n = p*4+t); frag (ui,ks):
    // n = w*64+ui*16+r15, c = ks*32+g4*8+e
    const float* xb = x + (long)b * 49600;
    bf16x8 Areg[4][8];
#pragma unroll
    for (int ui = 0; ui < 4; ++ui) {
        int n = w * 64 + ui * 16 + r15;
        const float* xn = xb + n;
        bool nok = (n < 200);
#pragma unroll
        for (int ks = 0; ks < 8; ++ks) {
            bf16x8 fr;
#pragma unroll
            for (int e = 0; e < 8; ++e) {
                int c = ks * 32 + g4 * 8 + e;
                float v = (nok && c < 248) ? xn[(long)c * 200] : 0.f;
                fr[e] = (bf16_t)v;
            }
            Areg[ui][ks] = fr;
        }
    }
    // no barrier: phase-0 pads are disjoint from all real writes; first pad
    // reads happen after the head-0 barriers below.

    // ================= head loop =================
    for (int h = 0; h < 8; ++h) {
        // ---- qkv GEMM: all 6 m-tiles, Wf frags double-buffered ----
        const bf16_t* wf = Wf + ((long)(h * 48) << 9) + lane * 8;
        bf16x8 Bc[8], Bn[8];
#pragma unroll
        for (int ks = 0; ks < 8; ++ks)
            Bc[ks] = *(const bf16x8*)(wf + (ks << 9));
#pragma unroll
        for (int m = 0; m < 6; ++m) {
            if (m < 5) {
#pragma unroll
                for (int ks = 0; ks < 8; ++ks)
                    Bn[ks] = *(const bf16x8*)(wf + (((m + 1) * 8 + ks) << 9));
            }
            f32x4 acc[4];
#pragma unroll
            for (int ui = 0; ui < 4; ++ui) acc[ui] = f32x4{0.f, 0.f, 0.f, 0.f};
#pragma unroll
            for (int ks = 0; ks < 8; ++ks)
#pragma unroll
                for (int ui = 0; ui < 4; ++ui)
                    acc[ui] = mfma16(Areg[ui][ks], Bc[ks], acc[ui]);

            int s = m >> 1;
            int d = ((m & 1) << 4) + r15;          // 0..31
            float bias = bp[h * 96 + m * 16 + r15];
            if (d < 31) {
#pragma unroll
                for (int ui = 0; ui < 4; ++ui) {
                    int p = (w * 4 + ui) * 4 + g4;
                    if (p >= 50) continue;
                    float a0 = acc[ui][0] + bias, a1 = acc[ui][1] + bias;
                    float a2 = acc[ui][2] + bias, a3 = acc[ui][3] + bias;
                    if (s < 2) {
                        bf16x4 pk = {(bf16_t)a0, (bf16_t)a1, (bf16_t)a2, (bf16_t)a3};
                        char* base = (s == 0) ? (char*)&QH[0][0] : (char*)&KH[0][0];
                        int chunk = (d >> 1) ^ (p & 7);
                        *(bf16x4*)(base + p * 256 + chunk * 16 + ((d & 1) << 3)) = pk;
                    } else {
                        int chunk = ((p >> 3) ^ (d & 7)) << 4;
                        char* vbase = (char*)&VT[0][0] + (d * 4) * 128 + chunk + (p & 7) * 2;
                        *(bf16_t*)(vbase)       = (bf16_t)a0;
                        *(bf16_t*)(vbase + 128) = (bf16_t)a1;
                        *(bf16_t*)(vbase + 256) = (bf16_t)a2;
                        *(bf16_t*)(vbase + 384) = (bf16_t)a3;
                    }
                }
            }
#pragma unroll
            for (int ks = 0; ks < 8; ++ks) Bc[ks] = Bn[ks];
        }
        __syncthreads();   // qkv tiles ready for all waves

        // ---- scores + softmax (wave-private q-rows w*16..w*16+15) ----
        bf16x8 Afr[4];
        {
            int p = w * 16 + r15;
            int hp = p & 7;
#pragma unroll
            for (int ks = 0; ks < 4; ++ks)
                Afr[ks] = *(const bf16x8*)((char*)&QH[0][0] + p * 256 + ((((ks << 2) | g4) ^ hp) << 4));
        }
        // dots: all 4 key tiles -> LS
#pragma unroll
        for (int ct = 0; ct < 4; ++ct) {
            int c = ct * 16 + r15;
            int hc = c & 7;
            f32x4 s = f32x4{0.f, 0.f, 0.f, 0.f};
#pragma unroll
            for (int ks = 0; ks < 4; ++ks) {
                bf16x8 Bf = *(const bf16x8*)((char*)&KH[0][0] + c * 256 + ((((ks << 2) | g4) ^ hc) << 4));
                s = mfma16(Afr[ks], Bf, s);
            }
            if (c < 50) {
#pragma unroll
                for (int j = 0; j < 4; ++j) {
                    int qrow = w * 16 + g4 * 4 + j;
                    if (qrow < 50) LS[qrow][c] = s[j];
                }
            }
        }
        wave_lds_fence();
        // rel bias: rt 0..6, rolling prefetch; scatter-add jj = r + qrow - 49
        {
            const bf16_t* rf = relf + lane * 8;
            bf16x8 R0[4], R1[4];
#pragma unroll
            for (int ks = 0; ks < 4; ++ks) R0[ks] = *(const bf16x8*)(rf + (ks << 9));
            for (int rt = 0; rt < 7; ++rt) {
                if (rt < 6) {
#pragma unroll
                    for (int ks = 0; ks < 4; ++ks)
                        R1[ks] = *(const bf16x8*)(rf + (((rt + 1) * 4 + ks) << 9));
                }
                f32x4 s = f32x4{0.f, 0.f, 0.f, 0.f};
#pragma unroll
                for (int ks = 0; ks < 4; ++ks) s = mfma16(Afr[ks], R0[ks], s);
                int r = rt * 16 + r15;
#pragma unroll
                for (int j = 0; j < 4; ++j) {
                    int qrow = w * 16 + g4 * 4 + j;
                    int jj = r + qrow - 49;
                    if (qrow < 50 && jj >= 0 && jj < 50) LS[qrow][jj] += s[j];
                }
#pragma unroll
                for (int ks = 0; ks < 4; ++ks) R0[ks] = R1[ks];
            }
        }
        wave_lds_fence();
        // softmax: 4 lanes per row, rows w*16.. (guard <50)
        {
            int row = w * 16 + (lane >> 2);
            int quad = lane & 3;
            if (row < 50) {
                float mx = -1e30f;
                for (int jj = quad; jj < 50; jj += 4) mx = fmaxf(mx, LS[row][jj]);
                mx = fmaxf(mx, __shfl_xor(mx, 1));
                mx = fmaxf(mx, __shfl_xor(mx, 2));
                float sum = 0.f;
                for (int jj = quad; jj < 50; jj += 4) {
                    float e = __expf((LS[row][jj] - mx) * SCALE);
                    LS[row][jj] = e;
                    sum += e;
                }
                sum += __shfl_xor(sum, 1);
                sum += __shfl_xor(sum, 2);
                float rs = 1.f / sum;
                int hrow = row & 7;
                for (int jj = quad; jj < 64; jj += 4) {
                    float v = (jj < 50) ? LS[row][jj] * rs : 0.f;
                    *(bf16_t*)((char*)&AS[0][0] + row * 128 + (((jj >> 3) ^ hrow) << 4) + (jj & 7) * 2) = (bf16_t)v;
                }
            }
        }
        __syncthreads();   // AS/VT ready for all waves

        // ---- PV: wave w owns i-tiles {2w, 2w+1}; all 4 p-tiles ----
#pragma unroll
        for (int ii = 0; ii < 2; ++ii) {
            int it = w * 2 + ii;
            int irow = it * 16 + r15;
            int hv = (irow >> 2) & 7;
            bf16x8 Av[2];
#pragma unroll
            for (int ks = 0; ks < 2; ++ks)
                Av[ks] = *(const bf16x8*)((char*)&VT[0][0] + irow * 128 + ((((ks << 2) | g4) ^ hv) << 4));
            int dd = it * 4 + g4;
#pragma unroll
            for (int pt = 0; pt < 4; ++pt) {
                int prow = pt * 16 + r15;
                int hp2 = prow & 7;
                f32x4 po = f32x4{0.f, 0.f, 0.f, 0.f};
#pragma unroll
                for (int ks = 0; ks < 2; ++ks) {
                    bf16x8 Bs = *(const bf16x8*)((char*)&AS[0][0] + prow * 128 + ((((ks << 2) | g4) ^ hp2) << 4));
                    po = mfma16(Av[ks], Bs, po);
                }
                if (dd < 31 && prow < 50)
                    *(f32x4*)(out + ((long)b * 248 + h * 31 + dd) * 200 + prow * 4) = po;
            }
        }
        __syncthreads();   // protect QH/KH/VT/AS/LS rewrite by next head
    }
}

// ---------------------------------------------------------------------------
extern "C" void kernel_launch(void* const* d_in, const int* in_sizes, int n_in,
                              void* d_out, int out_size, void* d_ws, size_t ws_size,
                              hipStream_t stream)
{
    const float* x   = (const float*)d_in[0];
    const float* wq  = (const float*)d_in[1];
    const float* bq  = (const float*)d_in[2];
    const float* rel = (const float*)d_in[3];
    float* out = (float*)d_out;

    char* ws = (char*)d_ws;
    bf16_t* Wf   = (bf16_t*)ws;                    // 196,608 elems = 393,216 B
    bf16_t* relf = (bf16_t*)(ws + 393216);         // 14,336 elems  = 28,672 B
    float*  bp   = (float*)(ws + 421888);          // 768 f32       = 3,072 B

    const int B = in_sizes[0] / 49600;

    prep_kernel<<<dim3(828), dim3(256), 0, stream>>>(wq, bq, rel, Wf, relf, bp);
    fused_kernel<<<dim3(B), dim3(256), 0, stream>>>(x, Wf, relf, bp, out);
}